// Round 2
// baseline (26.377 us; speedup 1.0000x reference)
//
#include <hip/hip_runtime.h>
#include <math.h>

// LowPassFilter: time-varying windowed-sinc FIR, 33 taps (taps 0 and 32 are
// zero due to the Hann window), filter row depends only on t + scalars.
// out[b,t] = sum_{j=1}^{31} c[t,j] * x[b, t+16-j]   (zero-padded)

constexpr int   HALF   = 16;
constexpr int   FSZ    = 33;          // FILTER_SIZE
constexpr float PI_F   = 3.14159265358979323846f;
constexpr int   BLOCK  = 256;
constexpr int   ROWS_PER_BLOCK = 8;   // batch rows handled per block (grid.y = B/8)

template <bool CHECK>
__device__ __forceinline__ void lpf_body(const float* __restrict__ x,
                                         float* __restrict__ out,
                                         float alpha, float beta,
                                         int n, int t, int row0)
{
    // ---- per-t filter coefficients (match reference fp32 arithmetic) ----
    const float cutoff = (PI_F / 4.0f + alpha * sinf(beta * (float)t / 8000.0f))
                         / (2.0f * PI_F);

    float c[FSZ];           // taps 1..31 used (0 and 32 are exactly zero)
    float sum = 0.0f;
    #pragma unroll
    for (int j = 1; j < FSZ - 1; ++j) {
        const float w   = 0.5f - 0.5f * cosf((2.0f * PI_F / (float)(FSZ - 1)) * (float)j);
        const float tm  = (float)(j - HALF);
        float s;
        if (j == HALF) {
            s = 1.0f;
        } else {
            const float arg = 2.0f * PI_F * cutoff * tm;
            s = sinf(arg) / arg;
        }
        const float f = 2.0f * cutoff * w * s;
        c[j] = f;
        sum += f;
    }
    const float inv = 1.0f / sum;
    #pragma unroll
    for (int j = 1; j < FSZ - 1; ++j) c[j] *= inv;

    // ---- apply across ROWS_PER_BLOCK batch rows ----
    for (int r = 0; r < ROWS_PER_BLOCK; ++r) {
        const float* __restrict__ base = x + (size_t)(row0 + r) * (size_t)n;
        float acc = 0.0f;
        #pragma unroll
        for (int j = 1; j < FSZ - 1; ++j) {
            const int idx = t + HALF - j;      // in [t-15, t+15]
            float v;
            if (CHECK) {
                v = (idx >= 0 && idx < n) ? base[idx] : 0.0f;
            } else {
                v = base[idx];
            }
            acc = fmaf(c[j], v, acc);
        }
        out[(size_t)(row0 + r) * (size_t)n + t] = acc;
    }
}

__global__ __launch_bounds__(BLOCK)
void LowPassFilter_53661321396356_kernel(const float* __restrict__ x,
                                         const float* __restrict__ alpha_p,
                                         const float* __restrict__ beta_p,
                                         float* __restrict__ out,
                                         int n)
{
    const int t = blockIdx.x * BLOCK + threadIdx.x;
    if (t >= n) return;
    const int row0  = blockIdx.y * ROWS_PER_BLOCK;
    const float alpha = alpha_p[0];
    const float beta  = beta_p[0];

    // Only the first and last column-blocks can touch out-of-range indices
    // (idx in [t-15, t+15]); everything else takes the unchecked fast path.
    if (blockIdx.x == 0 || blockIdx.x == gridDim.x - 1) {
        lpf_body<true >(x, out, alpha, beta, n, t, row0);
    } else {
        lpf_body<false>(x, out, alpha, beta, n, t, row0);
    }
}

extern "C" void kernel_launch(void* const* d_in, const int* in_sizes, int n_in,
                              void* d_out, int out_size, void* d_ws, size_t ws_size,
                              hipStream_t stream) {
    const float* x       = (const float*)d_in[0];
    const float* alpha_p = (const float*)d_in[1];
    const float* beta_p  = (const float*)d_in[2];
    float*       out     = (float*)d_out;

    const int B = 64;                        // batch (setup_inputs fixed)
    const int n = in_sizes[0] / B;           // 32768 columns

    dim3 grid((n + BLOCK - 1) / BLOCK, B / ROWS_PER_BLOCK);
    dim3 block(BLOCK);
    LowPassFilter_53661321396356_kernel<<<grid, block, 0, stream>>>(
        x, alpha_p, beta_p, out, n);
}

// Round 3
// 23.881 us; speedup vs baseline: 1.1045x; 1.1045x over previous
//
#include <hip/hip_runtime.h>
#include <math.h>

// Time-varying windowed-sinc FIR, 33 taps. Key algebra:
//   cutoff(t) = (pi/4 + alpha*sin(beta*t/8000)) / (2*pi)
//   theta(t)  = 2*pi*cutoff = pi/4 + alpha*sin(beta*t/8000)
//   tap j=16+k (k=-16..16):  f = 2*cutoff * w_k * sinc(theta*k)
//     k==0: f0 = 2*cutoff = theta/pi
//     k!=0: f  = (theta/pi) * w_k * sin(theta*k)/(theta*k) = w_k*sin(k*theta)/(pi*k)
//   Window is Hann -> w_{+-16}=0 (taps 0,32 vanish), and filter is SYMMETRIC
//   (w even, sinc even), so reversal is identity and only k=0..15 matter:
//   out[b,t] = C0*x[t] + sum_{k=1..15} Ck*(x[t-k]+x[t+k])   (normalized, 0-pad)
//   sin(k*theta) via Chebyshev recurrence: s_k = 2cos(theta)*s_{k-1} - s_{k-2}
//   -> 3 transcendentals per output column instead of 31 sinf.

constexpr int   HALF  = 16;
constexpr int   BLOCK = 256;
constexpr int   VEC   = 4;   // output columns per thread (float4)
constexpr int   ROWS  = 4;   // batch rows per block
constexpr float PI_F  = 3.14159265358979323846f;
constexpr double PI_D = 3.14159265358979323846;

// W_TAB[k] = (0.5 + 0.5*cos(pi*k/16)) / (pi*k)  — compile-time doubles.
constexpr float W_TAB[16] = {
    0.0f, // k=0 handled separately (f0 = theta/pi)
    (float)((0.5 + 0.5 *  0.98078528040323044) / (PI_D *  1.0)),
    (float)((0.5 + 0.5 *  0.92387953251128674) / (PI_D *  2.0)),
    (float)((0.5 + 0.5 *  0.83146961230254524) / (PI_D *  3.0)),
    (float)((0.5 + 0.5 *  0.70710678118654752) / (PI_D *  4.0)),
    (float)((0.5 + 0.5 *  0.55557023301960222) / (PI_D *  5.0)),
    (float)((0.5 + 0.5 *  0.38268343236508977) / (PI_D *  6.0)),
    (float)((0.5 + 0.5 *  0.19509032201612827) / (PI_D *  7.0)),
    (float)((0.5 + 0.5 *  0.0                ) / (PI_D *  8.0)),
    (float)((0.5 + 0.5 * -0.19509032201612827) / (PI_D *  9.0)),
    (float)((0.5 + 0.5 * -0.38268343236508977) / (PI_D * 10.0)),
    (float)((0.5 + 0.5 * -0.55557023301960222) / (PI_D * 11.0)),
    (float)((0.5 + 0.5 * -0.70710678118654752) / (PI_D * 12.0)),
    (float)((0.5 + 0.5 * -0.83146961230254524) / (PI_D * 13.0)),
    (float)((0.5 + 0.5 * -0.92387953251128674) / (PI_D * 14.0)),
    (float)((0.5 + 0.5 * -0.98078528040323044) / (PI_D * 15.0)),
};

template <bool CHECK>
__device__ __forceinline__ void lpf_body(const float* __restrict__ x,
                                         float* __restrict__ out,
                                         float alpha, float beta,
                                         int n, int t0, int row0)
{
    // ---- coefficients for the VEC output columns t0..t0+3 ----
    float C[VEC][16];
    #pragma unroll
    for (int o = 0; o < VEC; ++o) {
        const float tf    = (float)(t0 + o);
        const float theta = 0.25f * PI_F + alpha * sinf(beta * tf * (1.0f / 8000.0f));
        float s1, c1;
        sincosf(theta, &s1, &c1);

        float f[16];
        f[0] = theta * (float)(1.0 / PI_D);
        f[1] = s1 * W_TAB[1];
        const float two_c = 2.0f * c1;
        float skm1 = s1, skm2 = 0.0f;
        #pragma unroll
        for (int k = 2; k < 16; ++k) {
            const float sk = fmaf(two_c, skm1, -skm2);   // sin(k*theta)
            f[k] = sk * W_TAB[k];
            skm2 = skm1; skm1 = sk;
        }
        float sum = f[0];
        #pragma unroll
        for (int k = 1; k < 16; ++k) sum += 2.0f * f[k];
        const float inv = 1.0f / sum;
        #pragma unroll
        for (int k = 0; k < 16; ++k) C[o][k] = f[k] * inv;
    }

    // ---- FIR across ROWS batch rows ----
    for (int r = 0; r < ROWS; ++r) {
        const float* __restrict__ base = x + (size_t)(row0 + r) * (size_t)n;
        float w[36];                         // x[t0-16 .. t0+19]
        if (CHECK) {
            #pragma unroll
            for (int i = 0; i < 36; ++i) {
                const int idx = t0 - 16 + i;
                w[i] = (idx >= 0 && idx < n) ? base[idx] : 0.0f;
            }
        } else {
            const float4* __restrict__ p = (const float4*)(base + t0 - 16);
            #pragma unroll
            for (int q = 0; q < 9; ++q) {
                const float4 v = p[q];
                w[4*q+0] = v.x; w[4*q+1] = v.y; w[4*q+2] = v.z; w[4*q+3] = v.w;
            }
        }

        float4 res;
        float* rp = &res.x;
        #pragma unroll
        for (int o = 0; o < VEC; ++o) {
            const int ci = o + 16;           // center index in w[]
            float acc = C[o][0] * w[ci];
            #pragma unroll
            for (int k = 1; k < 16; ++k)
                acc = fmaf(C[o][k], w[ci - k] + w[ci + k], acc);
            rp[o] = acc;
        }
        *(float4*)(out + (size_t)(row0 + r) * (size_t)n + t0) = res;
    }
}

__global__ __launch_bounds__(BLOCK)
void LowPassFilter_53661321396356_kernel(const float* __restrict__ x,
                                         const float* __restrict__ alpha_p,
                                         const float* __restrict__ beta_p,
                                         float* __restrict__ out,
                                         int n)
{
    const int t0 = (blockIdx.x * BLOCK + threadIdx.x) * VEC;
    if (t0 >= n) return;
    const int row0   = blockIdx.y * ROWS;
    const float alpha = alpha_p[0];
    const float beta  = beta_p[0];

    // Only first/last column-blocks can read out of range (window is +-15).
    if (blockIdx.x == 0 || blockIdx.x == gridDim.x - 1) {
        lpf_body<true >(x, out, alpha, beta, n, t0, row0);
    } else {
        lpf_body<false>(x, out, alpha, beta, n, t0, row0);
    }
}

extern "C" void kernel_launch(void* const* d_in, const int* in_sizes, int n_in,
                              void* d_out, int out_size, void* d_ws, size_t ws_size,
                              hipStream_t stream) {
    const float* x       = (const float*)d_in[0];
    const float* alpha_p = (const float*)d_in[1];
    const float* beta_p  = (const float*)d_in[2];
    float*       out     = (float*)d_out;

    const int B = 64;
    const int n = in_sizes[0] / B;           // 32768

    dim3 grid((n + BLOCK * VEC - 1) / (BLOCK * VEC), B / ROWS);   // (32, 16)
    dim3 block(BLOCK);
    LowPassFilter_53661321396356_kernel<<<grid, block, 0, stream>>>(
        x, alpha_p, beta_p, out, n);
}